// Round 2
// baseline (1071.116 us; speedup 1.0000x reference)
//
#include <hip/hip_runtime.h>
#include <hip/hip_bf16.h>
#include <math.h>

// Problem constants
#define B_SZ   8
#define SEQ    2048
#define DMODEL 512
#define DEPTH  2
#define DSTATE 16
#define DCONV  4
#define DINNER 1024
#define DTRANK 32
#define ROWS   (B_SZ * SEQ)          // 16384
#define DBCW   (DTRANK + 2 * DSTATE) // 64

typedef unsigned short u16;
typedef float f32x4 __attribute__((ext_vector_type(4)));
typedef short bf16x8 __attribute__((ext_vector_type(8)));

// Fast device math (native v_exp/v_log/v_rcp)
__device__ __forceinline__ float silu_f(float v) {
    return v * __builtin_amdgcn_rcpf(1.f + __expf(-v));
}
__device__ __forceinline__ float softplus_f(float s) {
    return (s > 20.f) ? s : __logf(1.f + __expf(s));
}
__device__ __forceinline__ u16 f2b(float v) {
    __hip_bfloat16 h = __float2bfloat16(v);
    return *(u16*)&h;
}
__device__ __forceinline__ float b2f(u16 v) {
    __hip_bfloat16 h;
    *(u16*)&h = v;
    return __bfloat162float(h);
}
// sum across the 16-lane state group (DPP row rotate-reduce; all 16 lanes end with the total)
__device__ __forceinline__ float sum16(float x) {
    x += __int_as_float(__builtin_amdgcn_update_dpp(0, __float_as_int(x), 0x121, 0xf, 0xf, true));
    x += __int_as_float(__builtin_amdgcn_update_dpp(0, __float_as_int(x), 0x122, 0xf, 0xf, true));
    x += __int_as_float(__builtin_amdgcn_update_dpp(0, __float_as_int(x), 0x124, 0xf, 0xf, true));
    x += __int_as_float(__builtin_amdgcn_update_dpp(0, __float_as_int(x), 0x128, 0xf, 0xf, true));
    return x;
}

__device__ __forceinline__ void load_lds16(const void* g, void* l) {
    __builtin_amdgcn_global_load_lds(
        (const __attribute__((address_space(1))) unsigned int*)g,
        (__attribute__((address_space(3))) unsigned int*)l, 16, 0, 0);
}

// ---------------------------------------------------------------- fused weight conversion (1 launch/layer)
#define N_INW  (2 * DINNER * DMODEL)   // 2,097,152
#define N_OUTW (DMODEL * DINNER)       // 1,048,576
#define N_XW   (DBCW * DINNER)         //    65,536
__global__ __launch_bounds__(256) void conv_weights(const float* __restrict__ iw,
                                                    const float* __restrict__ ow,
                                                    const float* __restrict__ xw,
                                                    u16* __restrict__ inwbf,
                                                    u16* __restrict__ outwbf,
                                                    u16* __restrict__ xwbf) {
    int i = blockIdx.x * 256 + threadIdx.x;
    if (i < N_INW) inwbf[i] = f2b(iw[i]);
    else if (i < N_INW + N_OUTW) outwbf[i - N_INW] = f2b(ow[i - N_INW]);
    else if (i < N_INW + N_OUTW + N_XW) xwbf[i - N_INW - N_OUTW] = f2b(xw[i - N_INW - N_OUTW]);
}

// ---------------------------------------------------------------- LayerNorm (bf16 out)
__global__ __launch_bounds__(256) void ln_kernel(const float* __restrict__ x,
                                                 const float* __restrict__ w,
                                                 const float* __restrict__ b,
                                                 u16* __restrict__ out) {
    int r = blockIdx.x;
    int tid = threadIdx.x;
    const float* xr = x + (size_t)r * DMODEL;
    float2 v = *(const float2*)(xr + tid * 2);
    float s = v.x + v.y;
    float s2 = v.x * v.x + v.y * v.y;
    #pragma unroll
    for (int off = 1; off < 64; off <<= 1) {
        s  += __shfl_xor(s, off);
        s2 += __shfl_xor(s2, off);
    }
    __shared__ float ws[4], ws2[4];
    int wid = tid >> 6, lane = tid & 63;
    if (lane == 0) { ws[wid] = s; ws2[wid] = s2; }
    __syncthreads();
    float ts = ws[0] + ws[1] + ws[2] + ws[3];
    float ts2 = ws2[0] + ws2[1] + ws2[2] + ws2[3];
    float mean = ts * (1.f / DMODEL);
    float var = ts2 * (1.f / DMODEL) - mean * mean;
    float inv = rsqrtf(var + 1e-5f);
    out[(size_t)r * DMODEL + tid * 2]     = f2b((v.x - mean) * inv * w[tid * 2] + b[tid * 2]);
    out[(size_t)r * DMODEL + tid * 2 + 1] = f2b((v.y - mean) * inv * w[tid * 2 + 1] + b[tid * 2 + 1]);
}

// ---------------------------------------------------------------- in_proj bf16 MFMA GEMM
// xi_re[r,e]; sz_re[r,e] = silu(z) — both bf16, written from the epilogue.
__global__ __launch_bounds__(256) void gemm_in(const u16* __restrict__ A,
                                               const u16* __restrict__ W,
                                               u16* __restrict__ xi_re,
                                               u16* __restrict__ sz_re) {
    __shared__ u16 As[128 * 32];
    __shared__ u16 Bs[128 * 32];
    const int K = DMODEL;
    int tid = threadIdx.x;
    int wave = tid >> 6, lane = tid & 63;
    int wm = (wave >> 1) * 64, wn = (wave & 1) * 64;
    int m0 = blockIdx.y * 128, n0 = blockIdx.x * 128;
    int srow = lane >> 2, sseg = lane & 3;
    const u16* Ag = A + (size_t)(m0 + wave * 32 + srow) * K + sseg * 8;
    const u16* Wg = W + (size_t)(n0 + wave * 32 + srow) * K + sseg * 8;
    u16* Asw = As + wave * 32 * 32;
    u16* Bsw = Bs + wave * 32 * 32;

    f32x4 acc[4][4] = {};
    int col = lane & 15, quad = lane >> 4;

    for (int k0 = 0; k0 < K; k0 += 32) {
        __syncthreads();
        load_lds16(Ag + k0, Asw);
        load_lds16(Ag + k0 + (size_t)16 * K, Asw + 16 * 32);
        load_lds16(Wg + k0, Bsw);
        load_lds16(Wg + k0 + (size_t)16 * K, Bsw + 16 * 32);
        __syncthreads();
        bf16x8 af[4], bfr[4];
        #pragma unroll
        for (int i = 0; i < 4; ++i) {
            af[i]  = *(const bf16x8*)(As + (wm + i * 16 + col) * 32 + quad * 8);
            bfr[i] = *(const bf16x8*)(Bs + (wn + i * 16 + col) * 32 + quad * 8);
        }
        #pragma unroll
        for (int i = 0; i < 4; ++i)
            #pragma unroll
            for (int j = 0; j < 4; ++j)
                acc[i][j] = __builtin_amdgcn_mfma_f32_16x16x32_bf16(af[i], bfr[j], acc[i][j], 0, 0, 0);
    }
    bool is_z = (n0 >= DINNER);
    u16* dst = is_z ? sz_re : xi_re;
    int nb = n0 & (DINNER - 1);
    #pragma unroll
    for (int i = 0; i < 4; ++i) {
        int gm_base = m0 + wm + i * 16 + quad * 4;
        #pragma unroll
        for (int j = 0; j < 4; ++j) {
            int gn = nb + wn + j * 16 + col;
            #pragma unroll
            for (int r = 0; r < 4; ++r) {
                float v = acc[i][j][r];
                if (is_z) v = silu_f(v);
                dst[(size_t)(gm_base + r) * DINNER + gn] = f2b(v);
            }
        }
    }
}

// ---------------------------------------------------------------- out_proj bf16 MFMA GEMM (+residual, fp32 out)
__global__ __launch_bounds__(256) void gemm_out(const u16* __restrict__ A,
                                                const u16* __restrict__ W,
                                                const float* __restrict__ res,
                                                float* __restrict__ C) {
    __shared__ u16 As[128 * 32];
    __shared__ u16 Bs[128 * 32];
    const int K = DINNER, N = DMODEL;
    int tid = threadIdx.x;
    int wave = tid >> 6, lane = tid & 63;
    int wm = (wave >> 1) * 64, wn = (wave & 1) * 64;
    int m0 = blockIdx.y * 128, n0 = blockIdx.x * 128;
    int srow = lane >> 2, sseg = lane & 3;
    const u16* Ag = A + (size_t)(m0 + wave * 32 + srow) * K + sseg * 8;
    const u16* Wg = W + (size_t)(n0 + wave * 32 + srow) * K + sseg * 8;
    u16* Asw = As + wave * 32 * 32;
    u16* Bsw = Bs + wave * 32 * 32;

    f32x4 acc[4][4] = {};
    int col = lane & 15, quad = lane >> 4;

    for (int k0 = 0; k0 < K; k0 += 32) {
        __syncthreads();
        load_lds16(Ag + k0, Asw);
        load_lds16(Ag + k0 + (size_t)16 * K, Asw + 16 * 32);
        load_lds16(Wg + k0, Bsw);
        load_lds16(Wg + k0 + (size_t)16 * K, Bsw + 16 * 32);
        __syncthreads();
        bf16x8 af[4], bfr[4];
        #pragma unroll
        for (int i = 0; i < 4; ++i) {
            af[i]  = *(const bf16x8*)(As + (wm + i * 16 + col) * 32 + quad * 8);
            bfr[i] = *(const bf16x8*)(Bs + (wn + i * 16 + col) * 32 + quad * 8);
        }
        #pragma unroll
        for (int i = 0; i < 4; ++i)
            #pragma unroll
            for (int j = 0; j < 4; ++j)
                acc[i][j] = __builtin_amdgcn_mfma_f32_16x16x32_bf16(af[i], bfr[j], acc[i][j], 0, 0, 0);
    }
    #pragma unroll
    for (int i = 0; i < 4; ++i) {
        int gm_base = m0 + wm + i * 16 + quad * 4;
        #pragma unroll
        for (int j = 0; j < 4; ++j) {
            int gn = n0 + wn + j * 16 + col;
            #pragma unroll
            for (int r = 0; r < 4; ++r) {
                size_t off = (size_t)(gm_base + r) * N + gn;
                C[off] = acc[i][j][r] + res[off];
            }
        }
    }
}

// ---------------------------------------------------------------- x_proj bf16 MFMA GEMM (N=64)
__global__ __launch_bounds__(256) void gemm_xp_bf16(const u16* __restrict__ A,
                                                    const u16* __restrict__ W,
                                                    float* __restrict__ C) {
    __shared__ u16 As[128 * 32];
    __shared__ u16 Bs[64 * 32];
    int tid = threadIdx.x;
    int wave = tid >> 6, lane = tid & 63;
    int m0 = blockIdx.x * 128;
    int wm = wave * 32;
    int srow = lane >> 2, sseg = lane & 3;
    const u16* Ag = A + (size_t)(m0 + wm + srow) * DINNER + sseg * 8;
    const u16* Wg = W + (size_t)(wave * 16 + srow) * DINNER + sseg * 8;
    u16* Asw = As + wave * 32 * 32;
    u16* Bsw = Bs + wave * 16 * 32;

    f32x4 acc[2][4] = {};
    int col = lane & 15, quad = lane >> 4;

    for (int k0 = 0; k0 < DINNER; k0 += 32) {
        __syncthreads();
        load_lds16(Ag + k0, Asw);
        load_lds16(Ag + k0 + (size_t)16 * DINNER, Asw + 16 * 32);
        load_lds16(Wg + k0, Bsw);
        __syncthreads();
        bf16x8 af[2], bfr[4];
        #pragma unroll
        for (int i = 0; i < 2; ++i)
            af[i] = *(const bf16x8*)(As + (wm + i * 16 + col) * 32 + quad * 8);
        #pragma unroll
        for (int j = 0; j < 4; ++j)
            bfr[j] = *(const bf16x8*)(Bs + (j * 16 + col) * 32 + quad * 8);
        #pragma unroll
        for (int i = 0; i < 2; ++i)
            #pragma unroll
            for (int j = 0; j < 4; ++j)
                acc[i][j] = __builtin_amdgcn_mfma_f32_16x16x32_bf16(af[i], bfr[j], acc[i][j], 0, 0, 0);
    }
    #pragma unroll
    for (int i = 0; i < 2; ++i) {
        int gm_base = m0 + wm + i * 16 + quad * 4;
        #pragma unroll
        for (int j = 0; j < 4; ++j) {
            int gn = j * 16 + col;
            #pragma unroll
            for (int r = 0; r < 4; ++r)
                C[(size_t)(gm_base + r) * DBCW + gn] = acc[i][j][r];
        }
    }
}

// ---------------------------------------------------------------- u precompute + sz transpose
__global__ __launch_bounds__(256) void u_t_kernel(const u16* __restrict__ xi_re,
                                                  const u16* __restrict__ sz_re,
                                                  const float* __restrict__ cw,
                                                  const float* __restrict__ cb,
                                                  u16* __restrict__ ut,
                                                  u16* __restrict__ u_re,
                                                  u16* __restrict__ szt) {
    __shared__ float xt[67][65];
    __shared__ u16 uo[64][70];
    __shared__ u16 szo[64][70];
    int tid = threadIdx.x;
    int t0 = blockIdx.x * 64, e0 = blockIdx.y * 64, b = blockIdx.z;
    int er = tid & 63, rr = tid >> 6;
    for (int it = 0; it < 17; ++it) {
        int row = it * 4 + rr;
        if (row < 67) {
            int t = t0 + row - 3;
            xt[row][er] = (t >= 0) ? b2f(xi_re[((size_t)b * SEQ + t) * DINNER + e0 + er]) : 0.f;
        }
    }
    #pragma unroll
    for (int it = 0; it < 16; ++it) {
        int row = it * 4 + rr;
        szo[er][row] = sz_re[((size_t)b * SEQ + t0 + row) * DINNER + e0 + er];
    }
    __syncthreads();
    {
        int e = tid & 63, tg = tid >> 6;
        float4 w4 = *(const float4*)(cw + (e0 + e) * 4);
        float cbe = cb[e0 + e];
        int tl0 = tg * 16;
        float x3 = xt[tl0][e], x2 = xt[tl0 + 1][e], x1 = xt[tl0 + 2][e];
        #pragma unroll
        for (int i = 0; i < 16; ++i) {
            float x0 = xt[tl0 + i + 3][e];
            float u = silu_f(cbe + w4.x * x3 + w4.y * x2 + w4.z * x1 + w4.w * x0);
            x3 = x2; x2 = x1; x1 = x0;
            u16 ub = f2b(u);
            uo[e][tl0 + i] = ub;
            u_re[((size_t)b * SEQ + t0 + tl0 + i) * DINNER + e0 + e] = ub;
        }
    }
    __syncthreads();
    {
        int tl = tid & 63, eg = tid >> 6;
        #pragma unroll
        for (int i = 0; i < 16; ++i) {
            int ee = eg * 16 + i;
            ut[((size_t)b * DINNER + e0 + ee) * SEQ + t0 + tl] = uo[ee][tl];
            szt[((size_t)b * DINNER + e0 + ee) * SEQ + t0 + tl] = szo[ee][tl];
        }
    }
}

// ---------------------------------------------------------------- delta + p=dl*u + B/C precompute (merged)
// New: writes p = softplus(dt)*u as f32 (scan no longer converts/multiplies u per t),
// and B/C as f32 (scan drops 2 converts per t).
__global__ __launch_bounds__(256) void delta_bct_kernel(const float* __restrict__ dbc,
                                                        const float* __restrict__ dtw,
                                                        const float* __restrict__ dtb,
                                                        const u16* __restrict__ ut,
                                                        u16* __restrict__ dlt,
                                                        float* __restrict__ pt,
                                                        float* __restrict__ Btf,
                                                        float* __restrict__ Ctf) {
    __shared__ float wl[64 * 32];
    __shared__ float bl[64];
    int tid = threadIdx.x;
    int e0 = blockIdx.x * 64, t0 = blockIdx.y * 256, b = blockIdx.z;
    for (int i = tid; i < 64 * 32; i += 256) wl[i] = dtw[(size_t)e0 * DTRANK + i];
    if (tid < 64) bl[tid] = dtb[e0 + tid];
    float dreg[32];
    const float* dp = dbc + (size_t)(b * SEQ + t0 + tid) * DBCW;
    #pragma unroll
    for (int k = 0; k < 32; k += 4) {
        float4 v = *(const float4*)(dp + k);
        dreg[k] = v.x; dreg[k + 1] = v.y; dreg[k + 2] = v.z; dreg[k + 3] = v.w;
    }
    __syncthreads();
    for (int ep = 0; ep < 64; ++ep) {
        float s = bl[ep];
        #pragma unroll
        for (int k = 0; k < 32; ++k) s += dreg[k] * wl[ep * 32 + k];
        float dl = softplus_f(s);
        size_t idx = ((size_t)b * DINNER + e0 + ep) * SEQ + t0 + tid;
        dlt[idx] = f2b(dl);
        pt[idx] = dl * b2f(ut[idx]);
    }
    if (blockIdx.x == 0) {
        int t = t0 + tid;
        const float* dp2 = dbc + (size_t)(b * SEQ + t) * DBCW + DTRANK;
        #pragma unroll
        for (int nn = 0; nn < DSTATE; ++nn) {
            Btf[((size_t)b * DSTATE + nn) * SEQ + t] = dp2[nn];
            Ctf[((size_t)b * DSTATE + nn) * SEQ + t] = dp2[DSTATE + nn];
        }
    }
}

// ---------------------------------------------------------------- slim selective scan (VALU-minimized)
// Per t: 1 bf16 cvt (dl), mul dl*a2, exp2, mul p*B, fma h, mul h*C, 4 DPP, 1 mask-fma.
// p (=dl*u), B, C are f32 precomputed upstream; u/sz only touched once per 16-t chunk.
// block: 256 threads = 16 (b,e) pairs x 16 states. 512 blocks.
#define SCHUNK 16

__global__ __launch_bounds__(256, 2) void scan_fused(u16* __restrict__ y_re,
                                                     const float* __restrict__ pt,
                                                     const u16* __restrict__ dlt,
                                                     const float* __restrict__ Btf,
                                                     const float* __restrict__ Ctf,
                                                     const u16* __restrict__ ut,
                                                     const u16* __restrict__ szt,
                                                     const float* __restrict__ Alog,
                                                     const float* __restrict__ Dp) {
    int tid = threadIdx.x;
    int pair = tid >> 4, n = tid & 15;
    int blk = blockIdx.x;
    int b = blk >> 6;
    int e = ((blk & 63) << 4) + pair;
    float a2 = -__expf(Alog[e * DSTATE + n]) * 1.44269504f;   // fold log2e: dA = exp2(dl*a2)
    float dpe = Dp[e];
    const float* prow = pt  + ((size_t)b * DINNER + e) * SEQ;
    const u16* dlrow  = dlt + ((size_t)b * DINNER + e) * SEQ;
    const u16* urow   = ut  + ((size_t)b * DINNER + e) * SEQ;
    const u16* szrow  = szt + ((size_t)b * DINNER + e) * SEQ;
    const float* Brow = Btf + ((size_t)b * DSTATE + n) * SEQ;
    const float* Crow = Ctf + ((size_t)b * DSTATE + n) * SEQ;
    // lane n stores t = c*16+n for its pair: scatter over 16 rows
    u16* ystore = y_re + ((size_t)b * SEQ + n) * DINNER + e;

    // per-lane 0/1 mask: lane n keeps time-step j==n of each chunk (1 fma/t, no cmp/cndmask)
    float msk[16];
    #pragma unroll
    for (int j = 0; j < 16; ++j) msk[j] = (n == j) ? 1.f : 0.f;

    float h = 0.f;

    f32x4 PA0, PA1, PA2, PA3, BA0, BA1, BA2, BA3, CA0, CA1, CA2, CA3;
    f32x4 PB0, PB1, PB2, PB3, BB0, BB1, BB2, BB3, CB0, CB1, CB2, CB3;
    bf16x8 DA0, DA1, DB0, DB1;
    float uoA, szA, uoB, szB;

    auto load = [&](int c,
                    f32x4& P0, f32x4& P1, f32x4& P2, f32x4& P3,
                    bf16x8& d0, bf16x8& d1,
                    f32x4& B0, f32x4& B1, f32x4& B2, f32x4& B3,
                    f32x4& C0, f32x4& C1, f32x4& C2, f32x4& C3,
                    float& uo, float& szo) {
        const float* pr = prow + c * SCHUNK;
        P0 = *(const f32x4*)(pr);
        P1 = *(const f32x4*)(pr + 4);
        P2 = *(const f32x4*)(pr + 8);
        P3 = *(const f32x4*)(pr + 12);
        d0 = *(const bf16x8*)(dlrow + c * SCHUNK);
        d1 = *(const bf16x8*)(dlrow + c * SCHUNK + 8);
        const float* br = Brow + c * SCHUNK;
        B0 = *(const f32x4*)(br);
        B1 = *(const f32x4*)(br + 4);
        B2 = *(const f32x4*)(br + 8);
        B3 = *(const f32x4*)(br + 12);
        const float* cr = Crow + c * SCHUNK;
        C0 = *(const f32x4*)(cr);
        C1 = *(const f32x4*)(cr + 4);
        C2 = *(const f32x4*)(cr + 8);
        C3 = *(const f32x4*)(cr + 12);
        uo  = b2f(urow[c * SCHUNK + n]);    // lane n's own t
        szo = b2f(szrow[c * SCHUNK + n]);
    };
    auto proc = [&](int c,
                    f32x4 P0, f32x4 P1, f32x4 P2, f32x4 P3,
                    bf16x8 d0, bf16x8 d1,
                    f32x4 B0, f32x4 B1, f32x4 B2, f32x4 B3,
                    f32x4 C0, f32x4 C1, f32x4 C2, f32x4 C3,
                    float uo, float szo) {
        float keep = 0.f;
        #pragma unroll
        for (int g = 0; g < 4; ++g) {
            f32x4 Pv = (g == 0) ? P0 : (g == 1) ? P1 : (g == 2) ? P2 : P3;
            f32x4 Bv = (g == 0) ? B0 : (g == 1) ? B1 : (g == 2) ? B2 : B3;
            f32x4 Cv = (g == 0) ? C0 : (g == 1) ? C1 : (g == 2) ? C2 : C3;
            #pragma unroll
            for (int q = 0; q < 4; ++q) {
                int j = g * 4 + q;
                float dl = b2f((u16)((j < 8) ? d0[j] : d1[j - 8]));
                float dA = __builtin_amdgcn_exp2f(dl * a2);
                h = dA * h + Pv[q] * Bv[q];
                float yp = sum16(h * Cv[q]);
                keep += yp * msk[j];        // lane n keeps its own t's value
            }
        }
        ystore[(size_t)c * SCHUNK * DINNER] = f2b((keep + uo * dpe) * szo);
    };

    const int nc = SEQ / SCHUNK;   // 128, even
    load(0, PA0, PA1, PA2, PA3, DA0, DA1, BA0, BA1, BA2, BA3, CA0, CA1, CA2, CA3, uoA, szA);
    for (int c = 0; c < nc; c += 2) {
        load(c + 1, PB0, PB1, PB2, PB3, DB0, DB1, BB0, BB1, BB2, BB3, CB0, CB1, CB2, CB3, uoB, szB);
        proc(c, PA0, PA1, PA2, PA3, DA0, DA1, BA0, BA1, BA2, BA3, CA0, CA1, CA2, CA3, uoA, szA);
        if (c + 2 < nc) load(c + 2, PA0, PA1, PA2, PA3, DA0, DA1, BA0, BA1, BA2, BA3, CA0, CA1, CA2, CA3, uoA, szA);
        proc(c + 1, PB0, PB1, PB2, PB3, DB0, DB1, BB0, BB1, BB2, BB3, CB0, CB1, CB2, CB3, uoB, szB);
    }
}

// ---------------------------------------------------------------- launch
extern "C" void kernel_launch(void* const* d_in, const int* in_sizes, int n_in,
                              void* d_out, int out_size, void* d_ws, size_t ws_size,
                              hipStream_t stream) {
    const float* x_in   = (const float*)d_in[0];
    const float* ln_w   = (const float*)d_in[1];
    const float* ln_b   = (const float*)d_in[2];
    const float* inw    = (const float*)d_in[3];
    const float* convw  = (const float*)d_in[4];
    const float* convb  = (const float*)d_in[5];
    const float* xpw    = (const float*)d_in[6];
    const float* dtw    = (const float*)d_in[7];
    const float* dtb    = (const float*)d_in[8];
    const float* Alog   = (const float*)d_in[9];
    const float* Dp     = (const float*)d_in[10];
    const float* outw   = (const float*)d_in[11];
    float* out = (float*)d_out;

    // workspace carve-up — 212,860,928 B (exactly the proven footprint)
    char* p = (char*)d_ws;
    u16* xi_re = (u16*)p;               p += (size_t)ROWS * DINNER * 2;          //  33,554,432
    u16* sz_re = (u16*)p;               p += (size_t)ROWS * DINNER * 2;          //  33,554,432
    u16* y_re  = (u16*)p;               p += (size_t)ROWS * DINNER * 2;          //  33,554,432
    float* dbc = (float*)p;             p += (size_t)ROWS * DBCW * 4;            //   4,194,304
    u16* dlt   = (u16*)p;               p += (size_t)B_SZ * DINNER * SEQ * 2;    //  33,554,432
    u16* u_re  = dlt;                   // alias: u_re consumed by gemm_xp before delta writes dlt
    u16* Bt    = (u16*)p;               p += (size_t)B_SZ * DSTATE * SEQ * 2;    //     524,288
    u16* xwbf  = Bt;                    // alias: xwbf consumed by gemm_xp before delta_bct runs
    u16* Ct    = (u16*)p;               p += (size_t)B_SZ * DSTATE * SEQ * 2;    //     524,288
    (void)Ct;
    u16* ut    = (u16*)p;               p += (size_t)B_SZ * DINNER * SEQ * 2;    //  33,554,432
    u16* xnbf  = ut;                    // alias: xn (16.8 MB) dead before u_t writes ut
    u16* szt   = (u16*)p;               p += (size_t)B_SZ * DINNER * SEQ * 2;    //  33,554,432
    u16* inwbf = (u16*)p;               p += (size_t)N_INW * 2;                  //   4,194,304
    u16* outwbf = (u16*)p;              p += (size_t)N_OUTW * 2;                 //   2,097,152

    // f32 aliases (all stream-ordered dead-region reuse):
    //  pt  = dl*u  f32 [b,e,t], 67,108,864 B — spans xi_re+sz_re (both dead after u_t,
    //        written by delta_bct at step 5, read only by scan at step 6)
    //  Btf/Ctf f32 [b,n,t], 2 MB total — parked in inwbf region (dead after gemm_in;
    //        next layer's conv_weights rewrites it only after this layer's scan)
    float* pt  = (float*)xi_re;
    float* Btf = (float*)inwbf;
    float* Ctf = Btf + (size_t)B_SZ * DSTATE * SEQ;

    const dim3 blk256(256);
    const int n_conv = N_INW + N_OUTW + N_XW;

    for (int i = 0; i < DEPTH; ++i) {
        const float* x_cur = (i == 0) ? x_in : out;
        const float* lw  = ln_w  + (size_t)i * DMODEL;
        const float* lb  = ln_b  + (size_t)i * DMODEL;
        const float* iw  = inw   + (size_t)i * 2 * DINNER * DMODEL;
        const float* cw  = convw + (size_t)i * DINNER * DCONV;
        const float* cb  = convb + (size_t)i * DINNER;
        const float* xw  = xpw   + (size_t)i * DBCW * DINNER;
        const float* dw  = dtw   + (size_t)i * DINNER * DTRANK;
        const float* db  = dtb   + (size_t)i * DINNER;
        const float* Al  = Alog  + (size_t)i * DINNER * DSTATE;
        const float* Dpp = Dp    + (size_t)i * DINNER;
        const float* ow  = outw  + (size_t)i * DMODEL * DINNER;

        // 0. all weight conversions in one launch (xwbf parked in Bt region)
        conv_weights<<<(n_conv + 255) / 256, blk256, 0, stream>>>(
            iw, ow, xw, inwbf, outwbf, xwbf);
        // 1. LayerNorm -> bf16 (into ut region; dead before u_t writes)
        ln_kernel<<<ROWS, blk256, 0, stream>>>(x_cur, lw, lb, xnbf);
        // 2. in_proj (bf16 MFMA): xi_re = xn@iw_x^T, sz_re = silu(xn@iw_z^T)
        gemm_in<<<dim3(2 * DINNER / 128, ROWS / 128), blk256, 0, stream>>>(
            xnbf, inwbf, xi_re, sz_re);
        // 3. u precompute: ut[b,e,t] + u_re[r,e] + szt[b,e,t]
        u_t_kernel<<<dim3(SEQ / 64, DINNER / 64, B_SZ), blk256, 0, stream>>>(
            xi_re, sz_re, cw, cb, ut, u_re, szt);
        // 4. x_proj (bf16 MFMA, N=64): dbc = u_re @ xw^T
        gemm_xp_bf16<<<ROWS / 128, blk256, 0, stream>>>(u_re, xwbf, dbc);
        // 5. delta + p=dl*u (f32 into dead xi/sz regions) + B/C f32 (into dead inwbf region)
        delta_bct_kernel<<<dim3(DINNER / 64, SEQ / 256, B_SZ), blk256, 0, stream>>>(
            dbc, dw, db, ut, dlt, pt, Btf, Ctf);
        // 6. scan + register-keep gated output: y_re bf16
        scan_fused<<<(B_SZ * DINNER) / 16, blk256, 0, stream>>>(
            y_re, pt, dlt, Btf, Ctf, ut, szt, Al, Dpp);
        // 7. out_proj (bf16 MFMA) + residual
        gemm_out<<<dim3(DMODEL / 128, ROWS / 128), blk256, 0, stream>>>(
            y_re, outwbf, x_cur, out);
    }
}

// Round 3
// 862.450 us; speedup vs baseline: 1.2419x; 1.2419x over previous
//
#include <hip/hip_runtime.h>
#include <hip/hip_bf16.h>
#include <math.h>

// Problem constants
#define B_SZ   8
#define SEQ    2048
#define DMODEL 512
#define DEPTH  2
#define DSTATE 16
#define DCONV  4
#define DINNER 1024
#define DTRANK 32
#define ROWS   (B_SZ * SEQ)          // 16384
#define DBCW   (DTRANK + 2 * DSTATE) // 64

typedef unsigned short u16;
typedef float f32x4 __attribute__((ext_vector_type(4)));
typedef short bf16x8 __attribute__((ext_vector_type(8)));

// Fast device math (native v_exp/v_log/v_rcp)
__device__ __forceinline__ float silu_f(float v) {
    return v * __builtin_amdgcn_rcpf(1.f + __expf(-v));
}
__device__ __forceinline__ float softplus_f(float s) {
    return (s > 20.f) ? s : __logf(1.f + __expf(s));
}
__device__ __forceinline__ u16 f2b(float v) {
    __hip_bfloat16 h = __float2bfloat16(v);
    return *(u16*)&h;
}
__device__ __forceinline__ float b2f(u16 v) {
    __hip_bfloat16 h;
    *(u16*)&h = v;
    return __bfloat162float(h);
}
// sum across the 16-lane state group (DPP row rotate-reduce; all 16 lanes end with the total)
__device__ __forceinline__ float sum16(float x) {
    x += __int_as_float(__builtin_amdgcn_update_dpp(0, __float_as_int(x), 0x121, 0xf, 0xf, true));
    x += __int_as_float(__builtin_amdgcn_update_dpp(0, __float_as_int(x), 0x122, 0xf, 0xf, true));
    x += __int_as_float(__builtin_amdgcn_update_dpp(0, __float_as_int(x), 0x124, 0xf, 0xf, true));
    x += __int_as_float(__builtin_amdgcn_update_dpp(0, __float_as_int(x), 0x128, 0xf, 0xf, true));
    return x;
}

__device__ __forceinline__ void load_lds16(const void* g, void* l) {
    __builtin_amdgcn_global_load_lds(
        (const __attribute__((address_space(1))) unsigned int*)g,
        (__attribute__((address_space(3))) unsigned int*)l, 16, 0, 0);
}

// ---------------------------------------------------------------- fused weight conversion (1 launch/layer)
#define N_INW  (2 * DINNER * DMODEL)   // 2,097,152
#define N_OUTW (DMODEL * DINNER)       // 1,048,576
#define N_XW   (DBCW * DINNER)         //    65,536
__global__ __launch_bounds__(256) void conv_weights(const float* __restrict__ iw,
                                                    const float* __restrict__ ow,
                                                    const float* __restrict__ xw,
                                                    u16* __restrict__ inwbf,
                                                    u16* __restrict__ outwbf,
                                                    u16* __restrict__ xwbf) {
    int i = blockIdx.x * 256 + threadIdx.x;
    if (i < N_INW) inwbf[i] = f2b(iw[i]);
    else if (i < N_INW + N_OUTW) outwbf[i - N_INW] = f2b(ow[i - N_INW]);
    else if (i < N_INW + N_OUTW + N_XW) xwbf[i - N_INW - N_OUTW] = f2b(xw[i - N_INW - N_OUTW]);
}

// ---------------------------------------------------------------- LayerNorm (bf16 out)
__global__ __launch_bounds__(256) void ln_kernel(const float* __restrict__ x,
                                                 const float* __restrict__ w,
                                                 const float* __restrict__ b,
                                                 u16* __restrict__ out) {
    int r = blockIdx.x;
    int tid = threadIdx.x;
    const float* xr = x + (size_t)r * DMODEL;
    float2 v = *(const float2*)(xr + tid * 2);
    float s = v.x + v.y;
    float s2 = v.x * v.x + v.y * v.y;
    #pragma unroll
    for (int off = 1; off < 64; off <<= 1) {
        s  += __shfl_xor(s, off);
        s2 += __shfl_xor(s2, off);
    }
    __shared__ float ws[4], ws2[4];
    int wid = tid >> 6, lane = tid & 63;
    if (lane == 0) { ws[wid] = s; ws2[wid] = s2; }
    __syncthreads();
    float ts = ws[0] + ws[1] + ws[2] + ws[3];
    float ts2 = ws2[0] + ws2[1] + ws2[2] + ws2[3];
    float mean = ts * (1.f / DMODEL);
    float var = ts2 * (1.f / DMODEL) - mean * mean;
    float inv = rsqrtf(var + 1e-5f);
    out[(size_t)r * DMODEL + tid * 2]     = f2b((v.x - mean) * inv * w[tid * 2] + b[tid * 2]);
    out[(size_t)r * DMODEL + tid * 2 + 1] = f2b((v.y - mean) * inv * w[tid * 2 + 1] + b[tid * 2 + 1]);
}

// ---------------------------------------------------------------- in_proj bf16 MFMA GEMM
// xi_re[r,e]; sz_re[r,e] = silu(z) — both bf16, written from the epilogue.
__global__ __launch_bounds__(256) void gemm_in(const u16* __restrict__ A,
                                               const u16* __restrict__ W,
                                               u16* __restrict__ xi_re,
                                               u16* __restrict__ sz_re) {
    __shared__ u16 As[128 * 32];
    __shared__ u16 Bs[128 * 32];
    const int K = DMODEL;
    int tid = threadIdx.x;
    int wave = tid >> 6, lane = tid & 63;
    int wm = (wave >> 1) * 64, wn = (wave & 1) * 64;
    int m0 = blockIdx.y * 128, n0 = blockIdx.x * 128;
    int srow = lane >> 2, sseg = lane & 3;
    const u16* Ag = A + (size_t)(m0 + wave * 32 + srow) * K + sseg * 8;
    const u16* Wg = W + (size_t)(n0 + wave * 32 + srow) * K + sseg * 8;
    u16* Asw = As + wave * 32 * 32;
    u16* Bsw = Bs + wave * 32 * 32;

    f32x4 acc[4][4] = {};
    int col = lane & 15, quad = lane >> 4;

    for (int k0 = 0; k0 < K; k0 += 32) {
        __syncthreads();
        load_lds16(Ag + k0, Asw);
        load_lds16(Ag + k0 + (size_t)16 * K, Asw + 16 * 32);
        load_lds16(Wg + k0, Bsw);
        load_lds16(Wg + k0 + (size_t)16 * K, Bsw + 16 * 32);
        __syncthreads();
        bf16x8 af[4], bfr[4];
        #pragma unroll
        for (int i = 0; i < 4; ++i) {
            af[i]  = *(const bf16x8*)(As + (wm + i * 16 + col) * 32 + quad * 8);
            bfr[i] = *(const bf16x8*)(Bs + (wn + i * 16 + col) * 32 + quad * 8);
        }
        #pragma unroll
        for (int i = 0; i < 4; ++i)
            #pragma unroll
            for (int j = 0; j < 4; ++j)
                acc[i][j] = __builtin_amdgcn_mfma_f32_16x16x32_bf16(af[i], bfr[j], acc[i][j], 0, 0, 0);
    }
    bool is_z = (n0 >= DINNER);
    u16* dst = is_z ? sz_re : xi_re;
    int nb = n0 & (DINNER - 1);
    #pragma unroll
    for (int i = 0; i < 4; ++i) {
        int gm_base = m0 + wm + i * 16 + quad * 4;
        #pragma unroll
        for (int j = 0; j < 4; ++j) {
            int gn = nb + wn + j * 16 + col;
            #pragma unroll
            for (int r = 0; r < 4; ++r) {
                float v = acc[i][j][r];
                if (is_z) v = silu_f(v);
                dst[(size_t)(gm_base + r) * DINNER + gn] = f2b(v);
            }
        }
    }
}

// ---------------------------------------------------------------- out_proj bf16 MFMA GEMM (+residual, fp32 out)
__global__ __launch_bounds__(256) void gemm_out(const u16* __restrict__ A,
                                                const u16* __restrict__ W,
                                                const float* __restrict__ res,
                                                float* __restrict__ C) {
    __shared__ u16 As[128 * 32];
    __shared__ u16 Bs[128 * 32];
    const int K = DINNER, N = DMODEL;
    int tid = threadIdx.x;
    int wave = tid >> 6, lane = tid & 63;
    int wm = (wave >> 1) * 64, wn = (wave & 1) * 64;
    int m0 = blockIdx.y * 128, n0 = blockIdx.x * 128;
    int srow = lane >> 2, sseg = lane & 3;
    const u16* Ag = A + (size_t)(m0 + wave * 32 + srow) * K + sseg * 8;
    const u16* Wg = W + (size_t)(n0 + wave * 32 + srow) * K + sseg * 8;
    u16* Asw = As + wave * 32 * 32;
    u16* Bsw = Bs + wave * 32 * 32;

    f32x4 acc[4][4] = {};
    int col = lane & 15, quad = lane >> 4;

    for (int k0 = 0; k0 < K; k0 += 32) {
        __syncthreads();
        load_lds16(Ag + k0, Asw);
        load_lds16(Ag + k0 + (size_t)16 * K, Asw + 16 * 32);
        load_lds16(Wg + k0, Bsw);
        load_lds16(Wg + k0 + (size_t)16 * K, Bsw + 16 * 32);
        __syncthreads();
        bf16x8 af[4], bfr[4];
        #pragma unroll
        for (int i = 0; i < 4; ++i) {
            af[i]  = *(const bf16x8*)(As + (wm + i * 16 + col) * 32 + quad * 8);
            bfr[i] = *(const bf16x8*)(Bs + (wn + i * 16 + col) * 32 + quad * 8);
        }
        #pragma unroll
        for (int i = 0; i < 4; ++i)
            #pragma unroll
            for (int j = 0; j < 4; ++j)
                acc[i][j] = __builtin_amdgcn_mfma_f32_16x16x32_bf16(af[i], bfr[j], acc[i][j], 0, 0, 0);
    }
    #pragma unroll
    for (int i = 0; i < 4; ++i) {
        int gm_base = m0 + wm + i * 16 + quad * 4;
        #pragma unroll
        for (int j = 0; j < 4; ++j) {
            int gn = n0 + wn + j * 16 + col;
            #pragma unroll
            for (int r = 0; r < 4; ++r) {
                size_t off = (size_t)(gm_base + r) * N + gn;
                C[off] = acc[i][j][r] + res[off];
            }
        }
    }
}

// ---------------------------------------------------------------- x_proj bf16 MFMA GEMM (N=64)
__global__ __launch_bounds__(256) void gemm_xp_bf16(const u16* __restrict__ A,
                                                    const u16* __restrict__ W,
                                                    float* __restrict__ C) {
    __shared__ u16 As[128 * 32];
    __shared__ u16 Bs[64 * 32];
    int tid = threadIdx.x;
    int wave = tid >> 6, lane = tid & 63;
    int m0 = blockIdx.x * 128;
    int wm = wave * 32;
    int srow = lane >> 2, sseg = lane & 3;
    const u16* Ag = A + (size_t)(m0 + wm + srow) * DINNER + sseg * 8;
    const u16* Wg = W + (size_t)(wave * 16 + srow) * DINNER + sseg * 8;
    u16* Asw = As + wave * 32 * 32;
    u16* Bsw = Bs + wave * 16 * 32;

    f32x4 acc[2][4] = {};
    int col = lane & 15, quad = lane >> 4;

    for (int k0 = 0; k0 < DINNER; k0 += 32) {
        __syncthreads();
        load_lds16(Ag + k0, Asw);
        load_lds16(Ag + k0 + (size_t)16 * DINNER, Asw + 16 * 32);
        load_lds16(Wg + k0, Bsw);
        __syncthreads();
        bf16x8 af[2], bfr[4];
        #pragma unroll
        for (int i = 0; i < 2; ++i)
            af[i] = *(const bf16x8*)(As + (wm + i * 16 + col) * 32 + quad * 8);
        #pragma unroll
        for (int j = 0; j < 4; ++j)
            bfr[j] = *(const bf16x8*)(Bs + (j * 16 + col) * 32 + quad * 8);
        #pragma unroll
        for (int i = 0; i < 2; ++i)
            #pragma unroll
            for (int j = 0; j < 4; ++j)
                acc[i][j] = __builtin_amdgcn_mfma_f32_16x16x32_bf16(af[i], bfr[j], acc[i][j], 0, 0, 0);
    }
    #pragma unroll
    for (int i = 0; i < 2; ++i) {
        int gm_base = m0 + wm + i * 16 + quad * 4;
        #pragma unroll
        for (int j = 0; j < 4; ++j) {
            int gn = j * 16 + col;
            #pragma unroll
            for (int r = 0; r < 4; ++r)
                C[(size_t)(gm_base + r) * DBCW + gn] = acc[i][j][r];
        }
    }
}

// ---------------------------------------------------------------- u precompute (no sz staging — scan reads sz_re directly)
__global__ __launch_bounds__(256) void u_t_kernel(const u16* __restrict__ xi_re,
                                                  const float* __restrict__ cw,
                                                  const float* __restrict__ cb,
                                                  u16* __restrict__ ut,
                                                  u16* __restrict__ u_re) {
    __shared__ float xt[67][65];
    __shared__ u16 uo[64][70];
    int tid = threadIdx.x;
    int t0 = blockIdx.x * 64, e0 = blockIdx.y * 64, b = blockIdx.z;
    int er = tid & 63, rr = tid >> 6;
    for (int it = 0; it < 17; ++it) {
        int row = it * 4 + rr;
        if (row < 67) {
            int t = t0 + row - 3;
            xt[row][er] = (t >= 0) ? b2f(xi_re[((size_t)b * SEQ + t) * DINNER + e0 + er]) : 0.f;
        }
    }
    __syncthreads();
    {
        int e = tid & 63, tg = tid >> 6;
        float4 w4 = *(const float4*)(cw + (e0 + e) * 4);
        float cbe = cb[e0 + e];
        int tl0 = tg * 16;
        float x3 = xt[tl0][e], x2 = xt[tl0 + 1][e], x1 = xt[tl0 + 2][e];
        #pragma unroll
        for (int i = 0; i < 16; ++i) {
            float x0 = xt[tl0 + i + 3][e];
            float u = silu_f(cbe + w4.x * x3 + w4.y * x2 + w4.z * x1 + w4.w * x0);
            x3 = x2; x2 = x1; x1 = x0;
            u16 ub = f2b(u);
            uo[e][tl0 + i] = ub;
            u_re[((size_t)b * SEQ + t0 + tl0 + i) * DINNER + e0 + e] = ub;
        }
    }
    __syncthreads();
    {
        int tl = tid & 63, eg = tid >> 6;
        #pragma unroll
        for (int i = 0; i < 16; ++i) {
            int ee = eg * 16 + i;
            ut[((size_t)b * DINNER + e0 + ee) * SEQ + t0 + tl] = uo[ee][tl];
        }
    }
}

// ---------------------------------------------------------------- delta + B/C precompute (round-0 proven version, all bf16)
__global__ __launch_bounds__(256) void delta_bct_kernel(const float* __restrict__ dbc,
                                                        const float* __restrict__ dtw,
                                                        const float* __restrict__ dtb,
                                                        u16* __restrict__ dlt,
                                                        u16* __restrict__ Bt,
                                                        u16* __restrict__ Ct) {
    __shared__ float wl[64 * 32];
    __shared__ float bl[64];
    int tid = threadIdx.x;
    int e0 = blockIdx.x * 64, t0 = blockIdx.y * 256, b = blockIdx.z;
    for (int i = tid; i < 64 * 32; i += 256) wl[i] = dtw[(size_t)e0 * DTRANK + i];
    if (tid < 64) bl[tid] = dtb[e0 + tid];
    float dreg[32];
    const float* dp = dbc + (size_t)(b * SEQ + t0 + tid) * DBCW;
    #pragma unroll
    for (int k = 0; k < 32; k += 4) {
        float4 v = *(const float4*)(dp + k);
        dreg[k] = v.x; dreg[k + 1] = v.y; dreg[k + 2] = v.z; dreg[k + 3] = v.w;
    }
    __syncthreads();
    for (int ep = 0; ep < 64; ++ep) {
        float s = bl[ep];
        #pragma unroll
        for (int k = 0; k < 32; ++k) s += dreg[k] * wl[ep * 32 + k];
        dlt[((size_t)b * DINNER + e0 + ep) * SEQ + t0 + tid] = f2b(softplus_f(s));
    }
    if (blockIdx.x == 0) {
        int t = t0 + tid;
        const float* dp2 = dbc + (size_t)(b * SEQ + t) * DBCW + DTRANK;
        #pragma unroll
        for (int nn = 0; nn < DSTATE; ++nn) {
            Bt[((size_t)b * DSTATE + nn) * SEQ + t] = f2b(dp2[nn]);
            Ct[((size_t)b * DSTATE + nn) * SEQ + t] = f2b(dp2[DSTATE + nn]);
        }
    }
}

// ---------------------------------------------------------------- slim selective scan (byte-minimized)
// Streams: ut + dlt (bf16 [b,e,t]) + Bt/Ct (bf16, broadcast) — szt ELIMINATED:
// sz read directly from sz_re[r,e] at each lane's own t (1 scalar/16t, same scatter
// pattern as the y-store, L2-merged). D-term folded to 1 fma per chunk via mask-fma.
// block: 256 threads = 16 (b,e) pairs x 16 states. 512 blocks.
#define SCHUNK 16

__global__ __launch_bounds__(256, 2) void scan_fused(u16* __restrict__ y_re,
                                                     const u16* __restrict__ ut,
                                                     const u16* __restrict__ dlt,
                                                     const u16* __restrict__ Bt,
                                                     const u16* __restrict__ Ct,
                                                     const u16* __restrict__ sz_re,
                                                     const float* __restrict__ Alog,
                                                     const float* __restrict__ Dp) {
    int tid = threadIdx.x;
    int pair = tid >> 4, n = tid & 15;
    int blk = blockIdx.x;
    int b = blk >> 6;
    int e = ((blk & 63) << 4) + pair;
    float a2 = -__expf(Alog[e * DSTATE + n]) * 1.44269504f;   // fold log2e: dA = exp2(dl*a2)
    float dpe = Dp[e];
    const u16* urow  = ut  + ((size_t)b * DINNER + e) * SEQ;
    const u16* dlrow = dlt + ((size_t)b * DINNER + e) * SEQ;
    const u16* Brow  = Bt + ((size_t)b * DSTATE + n) * SEQ;
    const u16* Crow  = Ct + ((size_t)b * DSTATE + n) * SEQ;
    const u16* szcol = sz_re + (size_t)b * SEQ * DINNER + e;   // + t*DINNER
    // lane n stores t = c*16+n for its pair: scatter over 16 rows
    u16* ystore = y_re + ((size_t)b * SEQ + n) * DINNER + e;

    // per-lane 0/1 mask: lane n keeps time-step j==n of each chunk (1 fma/t, no cmp/cndmask)
    float msk[16];
    #pragma unroll
    for (int j = 0; j < 16; ++j) msk[j] = (n == j) ? 1.f : 0.f;

    float h = 0.f;
    bf16x8 Au0, Au1, Adl0, Adl1, AB0, AB1, AC0, AC1;
    bf16x8 Bu0, Bu1, Bdl0, Bdl1, BB0, BB1, BC0, BC1;
    float uoA, szA, uoB, szB;

    auto load = [&](int c, bf16x8& u0, bf16x8& u1, bf16x8& d0, bf16x8& d1,
                    bf16x8& b0, bf16x8& b1, bf16x8& c0, bf16x8& c1,
                    float& uo, float& szo) {
        u0 = *(const bf16x8*)(urow + c * SCHUNK);
        u1 = *(const bf16x8*)(urow + c * SCHUNK + 8);
        d0 = *(const bf16x8*)(dlrow + c * SCHUNK);
        d1 = *(const bf16x8*)(dlrow + c * SCHUNK + 8);
        b0 = *(const bf16x8*)(Brow + c * SCHUNK);
        b1 = *(const bf16x8*)(Brow + c * SCHUNK + 8);
        c0 = *(const bf16x8*)(Crow + c * SCHUNK);
        c1 = *(const bf16x8*)(Crow + c * SCHUNK + 8);
        uo  = b2f(urow[c * SCHUNK + n]);                          // lane n's own t
        szo = b2f(szcol[(size_t)(c * SCHUNK + n) * DINNER]);      // sz_re[r=b*SEQ+t, e]
    };
    auto proc = [&](int c, bf16x8 u0, bf16x8 u1, bf16x8 d0, bf16x8 d1,
                    bf16x8 b0, bf16x8 b1, bf16x8 c0, bf16x8 c1,
                    float uo, float szo) {
        float keep = 0.f;
        #pragma unroll
        for (int j = 0; j < SCHUNK; ++j) {
            float uf = b2f((u16)((j < 8) ? u0[j] : u1[j - 8]));
            float dl = b2f((u16)((j < 8) ? d0[j] : d1[j - 8]));
            float dA = __builtin_amdgcn_exp2f(dl * a2);
            h = dA * h + (dl * uf) * b2f((u16)((j < 8) ? b0[j] : b1[j - 8]));
            float yp = sum16(h * b2f((u16)((j < 8) ? c0[j] : c1[j - 8])));
            keep += yp * msk[j];   // lane n keeps its own t's value
        }
        ystore[(size_t)c * SCHUNK * DINNER] = f2b((keep + uo * dpe) * szo);
    };

    const int nc = SEQ / SCHUNK;   // 128, even
    load(0, Au0, Au1, Adl0, Adl1, AB0, AB1, AC0, AC1, uoA, szA);
    for (int c = 0; c < nc; c += 2) {
        load(c + 1, Bu0, Bu1, Bdl0, Bdl1, BB0, BB1, BC0, BC1, uoB, szB);
        proc(c, Au0, Au1, Adl0, Adl1, AB0, AB1, AC0, AC1, uoA, szA);
        if (c + 2 < nc) load(c + 2, Au0, Au1, Adl0, Adl1, AB0, AB1, AC0, AC1, uoA, szA);
        proc(c + 1, Bu0, Bu1, Bdl0, Bdl1, BB0, BB1, BC0, BC1, uoB, szB);
    }
}

// ---------------------------------------------------------------- launch
extern "C" void kernel_launch(void* const* d_in, const int* in_sizes, int n_in,
                              void* d_out, int out_size, void* d_ws, size_t ws_size,
                              hipStream_t stream) {
    const float* x_in   = (const float*)d_in[0];
    const float* ln_w   = (const float*)d_in[1];
    const float* ln_b   = (const float*)d_in[2];
    const float* inw    = (const float*)d_in[3];
    const float* convw  = (const float*)d_in[4];
    const float* convb  = (const float*)d_in[5];
    const float* xpw    = (const float*)d_in[6];
    const float* dtw    = (const float*)d_in[7];
    const float* dtb    = (const float*)d_in[8];
    const float* Alog   = (const float*)d_in[9];
    const float* Dp     = (const float*)d_in[10];
    const float* outw   = (const float*)d_in[11];
    float* out = (float*)d_out;

    // workspace carve-up — identical to the proven round-0 footprint (szt region now unused)
    char* p = (char*)d_ws;
    u16* xi_re = (u16*)p;               p += (size_t)ROWS * DINNER * 2;          //  33,554,432
    u16* sz_re = (u16*)p;               p += (size_t)ROWS * DINNER * 2;          //  33,554,432
    u16* y_re  = (u16*)p;               p += (size_t)ROWS * DINNER * 2;          //  33,554,432
    float* dbc = (float*)p;             p += (size_t)ROWS * DBCW * 4;            //   4,194,304
    u16* dlt   = (u16*)p;               p += (size_t)B_SZ * DINNER * SEQ * 2;    //  33,554,432
    u16* u_re  = dlt;                   // alias: u_re consumed by gemm_xp before delta writes dlt
    u16* Bt    = (u16*)p;               p += (size_t)B_SZ * DSTATE * SEQ * 2;    //     524,288
    u16* xwbf  = Bt;                    // alias: xwbf consumed by gemm_xp before delta_bct writes Bt
    u16* Ct    = (u16*)p;               p += (size_t)B_SZ * DSTATE * SEQ * 2;    //     524,288
    u16* ut    = (u16*)p;               p += (size_t)B_SZ * DINNER * SEQ * 2;    //  33,554,432
    u16* xnbf  = ut;                    // alias: xn (16.8 MB) dead before u_t writes ut
    u16* szt_unused = (u16*)p;          p += (size_t)B_SZ * DINNER * SEQ * 2;    //  33,554,432 (free)
    (void)szt_unused;
    u16* inwbf = (u16*)p;               p += (size_t)N_INW * 2;                  //   4,194,304
    u16* outwbf = (u16*)p;              p += (size_t)N_OUTW * 2;                 //   2,097,152

    const dim3 blk256(256);
    const int n_conv = N_INW + N_OUTW + N_XW;

    for (int i = 0; i < DEPTH; ++i) {
        const float* x_cur = (i == 0) ? x_in : out;
        const float* lw  = ln_w  + (size_t)i * DMODEL;
        const float* lb  = ln_b  + (size_t)i * DMODEL;
        const float* iw  = inw   + (size_t)i * 2 * DINNER * DMODEL;
        const float* cw  = convw + (size_t)i * DINNER * DCONV;
        const float* cb  = convb + (size_t)i * DINNER;
        const float* xw  = xpw   + (size_t)i * DBCW * DINNER;
        const float* dw  = dtw   + (size_t)i * DINNER * DTRANK;
        const float* db  = dtb   + (size_t)i * DINNER;
        const float* Al  = Alog  + (size_t)i * DINNER * DSTATE;
        const float* Dpp = Dp    + (size_t)i * DINNER;
        const float* ow  = outw  + (size_t)i * DMODEL * DINNER;

        // 0. all weight conversions in one launch (xwbf parked in Bt region)
        conv_weights<<<(n_conv + 255) / 256, blk256, 0, stream>>>(
            iw, ow, xw, inwbf, outwbf, xwbf);
        // 1. LayerNorm -> bf16 (into ut region; dead before u_t writes)
        ln_kernel<<<ROWS, blk256, 0, stream>>>(x_cur, lw, lb, xnbf);
        // 2. in_proj (bf16 MFMA): xi_re = xn@iw_x^T, sz_re = silu(xn@iw_z^T)
        gemm_in<<<dim3(2 * DINNER / 128, ROWS / 128), blk256, 0, stream>>>(
            xnbf, inwbf, xi_re, sz_re);
        // 3. u precompute: ut[b,e,t] + u_re[r,e] (no sz staging anymore)
        u_t_kernel<<<dim3(SEQ / 64, DINNER / 64, B_SZ), blk256, 0, stream>>>(
            xi_re, cw, cb, ut, u_re);
        // 4. x_proj (bf16 MFMA, N=64): dbc = u_re @ xw^T
        gemm_xp_bf16<<<ROWS / 128, blk256, 0, stream>>>(u_re, xwbf, dbc);
        // 5. delta + B/C precompute (overwrites u_re/xwbf regions, now dead)
        delta_bct_kernel<<<dim3(DINNER / 64, SEQ / 256, B_SZ), blk256, 0, stream>>>(
            dbc, dw, db, dlt, Bt, Ct);
        // 6. scan + register-keep gated output: y_re bf16 (sz from sz_re directly)
        scan_fused<<<(B_SZ * DINNER) / 16, blk256, 0, stream>>>(
            y_re, ut, dlt, Bt, Ct, sz_re, Al, Dpp);
        // 7. out_proj (bf16 MFMA) + residual
        gemm_out<<<dim3(DMODEL / 128, ROWS / 128), blk256, 0, stream>>>(
            y_re, outwbf, x_cur, out);
    }
}

// Round 4
// 860.911 us; speedup vs baseline: 1.2442x; 1.0018x over previous
//
#include <hip/hip_runtime.h>
#include <hip/hip_bf16.h>
#include <math.h>

// Problem constants
#define B_SZ   8
#define SEQ    2048
#define DMODEL 512
#define DEPTH  2
#define DSTATE 16
#define DCONV  4
#define DINNER 1024
#define DTRANK 32
#define ROWS   (B_SZ * SEQ)          // 16384
#define DBCW   (DTRANK + 2 * DSTATE) // 64

typedef unsigned short u16;
typedef float f32x4 __attribute__((ext_vector_type(4)));
typedef short bf16x8 __attribute__((ext_vector_type(8)));

// Fast device math (native v_exp/v_log/v_rcp)
__device__ __forceinline__ float silu_f(float v) {
    return v * __builtin_amdgcn_rcpf(1.f + __expf(-v));
}
__device__ __forceinline__ float softplus_f(float s) {
    return (s > 20.f) ? s : __logf(1.f + __expf(s));
}
__device__ __forceinline__ u16 f2b(float v) {
    __hip_bfloat16 h = __float2bfloat16(v);
    return *(u16*)&h;
}
__device__ __forceinline__ float b2f(u16 v) {
    __hip_bfloat16 h;
    *(u16*)&h = v;
    return __bfloat162float(h);
}
// sum across the 16-lane state group (DPP row rotate-reduce; all 16 lanes end with the total)
__device__ __forceinline__ float sum16(float x) {
    x += __int_as_float(__builtin_amdgcn_update_dpp(0, __float_as_int(x), 0x121, 0xf, 0xf, true));
    x += __int_as_float(__builtin_amdgcn_update_dpp(0, __float_as_int(x), 0x122, 0xf, 0xf, true));
    x += __int_as_float(__builtin_amdgcn_update_dpp(0, __float_as_int(x), 0x124, 0xf, 0xf, true));
    x += __int_as_float(__builtin_amdgcn_update_dpp(0, __float_as_int(x), 0x128, 0xf, 0xf, true));
    return x;
}

__device__ __forceinline__ void load_lds16(const void* g, void* l) {
    __builtin_amdgcn_global_load_lds(
        (const __attribute__((address_space(1))) unsigned int*)g,
        (__attribute__((address_space(3))) unsigned int*)l, 16, 0, 0);
}

// ---------------------------------------------------------------- fused weight conversion (1 launch/layer)
#define N_INW  (2 * DINNER * DMODEL)   // 2,097,152
#define N_OUTW (DMODEL * DINNER)       // 1,048,576
#define N_XW   (DBCW * DINNER)         //    65,536
__global__ __launch_bounds__(256) void conv_weights(const float* __restrict__ iw,
                                                    const float* __restrict__ ow,
                                                    const float* __restrict__ xw,
                                                    u16* __restrict__ inwbf,
                                                    u16* __restrict__ outwbf,
                                                    u16* __restrict__ xwbf) {
    int i = blockIdx.x * 256 + threadIdx.x;
    if (i < N_INW) inwbf[i] = f2b(iw[i]);
    else if (i < N_INW + N_OUTW) outwbf[i - N_INW] = f2b(ow[i - N_INW]);
    else if (i < N_INW + N_OUTW + N_XW) xwbf[i - N_INW - N_OUTW] = f2b(xw[i - N_INW - N_OUTW]);
}

// ---------------------------------------------------------------- LayerNorm (bf16 out)
__global__ __launch_bounds__(256) void ln_kernel(const float* __restrict__ x,
                                                 const float* __restrict__ w,
                                                 const float* __restrict__ b,
                                                 u16* __restrict__ out) {
    int r = blockIdx.x;
    int tid = threadIdx.x;
    const float* xr = x + (size_t)r * DMODEL;
    float2 v = *(const float2*)(xr + tid * 2);
    float s = v.x + v.y;
    float s2 = v.x * v.x + v.y * v.y;
    #pragma unroll
    for (int off = 1; off < 64; off <<= 1) {
        s  += __shfl_xor(s, off);
        s2 += __shfl_xor(s2, off);
    }
    __shared__ float ws[4], ws2[4];
    int wid = tid >> 6, lane = tid & 63;
    if (lane == 0) { ws[wid] = s; ws2[wid] = s2; }
    __syncthreads();
    float ts = ws[0] + ws[1] + ws[2] + ws[3];
    float ts2 = ws2[0] + ws2[1] + ws2[2] + ws2[3];
    float mean = ts * (1.f / DMODEL);
    float var = ts2 * (1.f / DMODEL) - mean * mean;
    float inv = rsqrtf(var + 1e-5f);
    out[(size_t)r * DMODEL + tid * 2]     = f2b((v.x - mean) * inv * w[tid * 2] + b[tid * 2]);
    out[(size_t)r * DMODEL + tid * 2 + 1] = f2b((v.y - mean) * inv * w[tid * 2 + 1] + b[tid * 2 + 1]);
}

// ---------------------------------------------------------------- in_proj bf16 MFMA GEMM
// xi_re[r,e]; sz_re[r,e] = silu(z) — both bf16, written from the epilogue.
__global__ __launch_bounds__(256) void gemm_in(const u16* __restrict__ A,
                                               const u16* __restrict__ W,
                                               u16* __restrict__ xi_re,
                                               u16* __restrict__ sz_re) {
    __shared__ u16 As[128 * 32];
    __shared__ u16 Bs[128 * 32];
    const int K = DMODEL;
    int tid = threadIdx.x;
    int wave = tid >> 6, lane = tid & 63;
    int wm = (wave >> 1) * 64, wn = (wave & 1) * 64;
    int m0 = blockIdx.y * 128, n0 = blockIdx.x * 128;
    int srow = lane >> 2, sseg = lane & 3;
    const u16* Ag = A + (size_t)(m0 + wave * 32 + srow) * K + sseg * 8;
    const u16* Wg = W + (size_t)(n0 + wave * 32 + srow) * K + sseg * 8;
    u16* Asw = As + wave * 32 * 32;
    u16* Bsw = Bs + wave * 32 * 32;

    f32x4 acc[4][4] = {};
    int col = lane & 15, quad = lane >> 4;

    for (int k0 = 0; k0 < K; k0 += 32) {
        __syncthreads();
        load_lds16(Ag + k0, Asw);
        load_lds16(Ag + k0 + (size_t)16 * K, Asw + 16 * 32);
        load_lds16(Wg + k0, Bsw);
        load_lds16(Wg + k0 + (size_t)16 * K, Bsw + 16 * 32);
        __syncthreads();
        bf16x8 af[4], bfr[4];
        #pragma unroll
        for (int i = 0; i < 4; ++i) {
            af[i]  = *(const bf16x8*)(As + (wm + i * 16 + col) * 32 + quad * 8);
            bfr[i] = *(const bf16x8*)(Bs + (wn + i * 16 + col) * 32 + quad * 8);
        }
        #pragma unroll
        for (int i = 0; i < 4; ++i)
            #pragma unroll
            for (int j = 0; j < 4; ++j)
                acc[i][j] = __builtin_amdgcn_mfma_f32_16x16x32_bf16(af[i], bfr[j], acc[i][j], 0, 0, 0);
    }
    bool is_z = (n0 >= DINNER);
    u16* dst = is_z ? sz_re : xi_re;
    int nb = n0 & (DINNER - 1);
    #pragma unroll
    for (int i = 0; i < 4; ++i) {
        int gm_base = m0 + wm + i * 16 + quad * 4;
        #pragma unroll
        for (int j = 0; j < 4; ++j) {
            int gn = nb + wn + j * 16 + col;
            #pragma unroll
            for (int r = 0; r < 4; ++r) {
                float v = acc[i][j][r];
                if (is_z) v = silu_f(v);
                dst[(size_t)(gm_base + r) * DINNER + gn] = f2b(v);
            }
        }
    }
}

// ---------------------------------------------------------------- out_proj bf16 MFMA GEMM (+residual, fp32 out)
__global__ __launch_bounds__(256) void gemm_out(const u16* __restrict__ A,
                                                const u16* __restrict__ W,
                                                const float* __restrict__ res,
                                                float* __restrict__ C) {
    __shared__ u16 As[128 * 32];
    __shared__ u16 Bs[128 * 32];
    const int K = DINNER, N = DMODEL;
    int tid = threadIdx.x;
    int wave = tid >> 6, lane = tid & 63;
    int wm = (wave >> 1) * 64, wn = (wave & 1) * 64;
    int m0 = blockIdx.y * 128, n0 = blockIdx.x * 128;
    int srow = lane >> 2, sseg = lane & 3;
    const u16* Ag = A + (size_t)(m0 + wave * 32 + srow) * K + sseg * 8;
    const u16* Wg = W + (size_t)(n0 + wave * 32 + srow) * K + sseg * 8;
    u16* Asw = As + wave * 32 * 32;
    u16* Bsw = Bs + wave * 32 * 32;

    f32x4 acc[4][4] = {};
    int col = lane & 15, quad = lane >> 4;

    for (int k0 = 0; k0 < K; k0 += 32) {
        __syncthreads();
        load_lds16(Ag + k0, Asw);
        load_lds16(Ag + k0 + (size_t)16 * K, Asw + 16 * 32);
        load_lds16(Wg + k0, Bsw);
        load_lds16(Wg + k0 + (size_t)16 * K, Bsw + 16 * 32);
        __syncthreads();
        bf16x8 af[4], bfr[4];
        #pragma unroll
        for (int i = 0; i < 4; ++i) {
            af[i]  = *(const bf16x8*)(As + (wm + i * 16 + col) * 32 + quad * 8);
            bfr[i] = *(const bf16x8*)(Bs + (wn + i * 16 + col) * 32 + quad * 8);
        }
        #pragma unroll
        for (int i = 0; i < 4; ++i)
            #pragma unroll
            for (int j = 0; j < 4; ++j)
                acc[i][j] = __builtin_amdgcn_mfma_f32_16x16x32_bf16(af[i], bfr[j], acc[i][j], 0, 0, 0);
    }
    #pragma unroll
    for (int i = 0; i < 4; ++i) {
        int gm_base = m0 + wm + i * 16 + quad * 4;
        #pragma unroll
        for (int j = 0; j < 4; ++j) {
            int gn = n0 + wn + j * 16 + col;
            #pragma unroll
            for (int r = 0; r < 4; ++r) {
                size_t off = (size_t)(gm_base + r) * N + gn;
                C[off] = acc[i][j][r] + res[off];
            }
        }
    }
}

// ---------------------------------------------------------------- x_proj bf16 MFMA GEMM (N=64)
__global__ __launch_bounds__(256) void gemm_xp_bf16(const u16* __restrict__ A,
                                                    const u16* __restrict__ W,
                                                    float* __restrict__ C) {
    __shared__ u16 As[128 * 32];
    __shared__ u16 Bs[64 * 32];
    int tid = threadIdx.x;
    int wave = tid >> 6, lane = tid & 63;
    int m0 = blockIdx.x * 128;
    int wm = wave * 32;
    int srow = lane >> 2, sseg = lane & 3;
    const u16* Ag = A + (size_t)(m0 + wm + srow) * DINNER + sseg * 8;
    const u16* Wg = W + (size_t)(wave * 16 + srow) * DINNER + sseg * 8;
    u16* Asw = As + wave * 32 * 32;
    u16* Bsw = Bs + wave * 16 * 32;

    f32x4 acc[2][4] = {};
    int col = lane & 15, quad = lane >> 4;

    for (int k0 = 0; k0 < DINNER; k0 += 32) {
        __syncthreads();
        load_lds16(Ag + k0, Asw);
        load_lds16(Ag + k0 + (size_t)16 * DINNER, Asw + 16 * 32);
        load_lds16(Wg + k0, Bsw);
        __syncthreads();
        bf16x8 af[2], bfr[4];
        #pragma unroll
        for (int i = 0; i < 2; ++i)
            af[i] = *(const bf16x8*)(As + (wm + i * 16 + col) * 32 + quad * 8);
        #pragma unroll
        for (int j = 0; j < 4; ++j)
            bfr[j] = *(const bf16x8*)(Bs + (j * 16 + col) * 32 + quad * 8);
        #pragma unroll
        for (int i = 0; i < 2; ++i)
            #pragma unroll
            for (int j = 0; j < 4; ++j)
                acc[i][j] = __builtin_amdgcn_mfma_f32_16x16x32_bf16(af[i], bfr[j], acc[i][j], 0, 0, 0);
    }
    #pragma unroll
    for (int i = 0; i < 2; ++i) {
        int gm_base = m0 + wm + i * 16 + quad * 4;
        #pragma unroll
        for (int j = 0; j < 4; ++j) {
            int gn = j * 16 + col;
            #pragma unroll
            for (int r = 0; r < 4; ++r)
                C[(size_t)(gm_base + r) * DBCW + gn] = acc[i][j][r];
        }
    }
}

// ---------------------------------------------------------------- u precompute + sz transpose (round-0 proven)
__global__ __launch_bounds__(256) void u_t_kernel(const u16* __restrict__ xi_re,
                                                  const u16* __restrict__ sz_re,
                                                  const float* __restrict__ cw,
                                                  const float* __restrict__ cb,
                                                  u16* __restrict__ ut,
                                                  u16* __restrict__ u_re,
                                                  u16* __restrict__ szt) {
    __shared__ float xt[67][65];
    __shared__ u16 uo[64][70];
    __shared__ u16 szo[64][70];
    int tid = threadIdx.x;
    int t0 = blockIdx.x * 64, e0 = blockIdx.y * 64, b = blockIdx.z;
    int er = tid & 63, rr = tid >> 6;
    for (int it = 0; it < 17; ++it) {
        int row = it * 4 + rr;
        if (row < 67) {
            int t = t0 + row - 3;
            xt[row][er] = (t >= 0) ? b2f(xi_re[((size_t)b * SEQ + t) * DINNER + e0 + er]) : 0.f;
        }
    }
    #pragma unroll
    for (int it = 0; it < 16; ++it) {
        int row = it * 4 + rr;
        szo[er][row] = sz_re[((size_t)b * SEQ + t0 + row) * DINNER + e0 + er];
    }
    __syncthreads();
    {
        int e = tid & 63, tg = tid >> 6;
        float4 w4 = *(const float4*)(cw + (e0 + e) * 4);
        float cbe = cb[e0 + e];
        int tl0 = tg * 16;
        float x3 = xt[tl0][e], x2 = xt[tl0 + 1][e], x1 = xt[tl0 + 2][e];
        #pragma unroll
        for (int i = 0; i < 16; ++i) {
            float x0 = xt[tl0 + i + 3][e];
            float u = silu_f(cbe + w4.x * x3 + w4.y * x2 + w4.z * x1 + w4.w * x0);
            x3 = x2; x2 = x1; x1 = x0;
            u16 ub = f2b(u);
            uo[e][tl0 + i] = ub;
            u_re[((size_t)b * SEQ + t0 + tl0 + i) * DINNER + e0 + e] = ub;
        }
    }
    __syncthreads();
    {
        int tl = tid & 63, eg = tid >> 6;
        #pragma unroll
        for (int i = 0; i < 16; ++i) {
            int ee = eg * 16 + i;
            ut[((size_t)b * DINNER + e0 + ee) * SEQ + t0 + tl] = uo[ee][tl];
            szt[((size_t)b * DINNER + e0 + ee) * SEQ + t0 + tl] = szo[ee][tl];
        }
    }
}

// ---------------------------------------------------------------- delta + B/C precompute (round-0 proven)
__global__ __launch_bounds__(256) void delta_bct_kernel(const float* __restrict__ dbc,
                                                        const float* __restrict__ dtw,
                                                        const float* __restrict__ dtb,
                                                        u16* __restrict__ dlt,
                                                        u16* __restrict__ Bt,
                                                        u16* __restrict__ Ct) {
    __shared__ float wl[64 * 32];
    __shared__ float bl[64];
    int tid = threadIdx.x;
    int e0 = blockIdx.x * 64, t0 = blockIdx.y * 256, b = blockIdx.z;
    for (int i = tid; i < 64 * 32; i += 256) wl[i] = dtw[(size_t)e0 * DTRANK + i];
    if (tid < 64) bl[tid] = dtb[e0 + tid];
    float dreg[32];
    const float* dp = dbc + (size_t)(b * SEQ + t0 + tid) * DBCW;
    #pragma unroll
    for (int k = 0; k < 32; k += 4) {
        float4 v = *(const float4*)(dp + k);
        dreg[k] = v.x; dreg[k + 1] = v.y; dreg[k + 2] = v.z; dreg[k + 3] = v.w;
    }
    __syncthreads();
    for (int ep = 0; ep < 64; ++ep) {
        float s = bl[ep];
        #pragma unroll
        for (int k = 0; k < 32; ++k) s += dreg[k] * wl[ep * 32 + k];
        dlt[((size_t)b * DINNER + e0 + ep) * SEQ + t0 + tid] = f2b(softplus_f(s));
    }
    if (blockIdx.x == 0) {
        int t = t0 + tid;
        const float* dp2 = dbc + (size_t)(b * SEQ + t) * DBCW + DTRANK;
        #pragma unroll
        for (int nn = 0; nn < DSTATE; ++nn) {
            Bt[((size_t)b * DSTATE + nn) * SEQ + t] = f2b(dp2[nn]);
            Ct[((size_t)b * DSTATE + nn) * SEQ + t] = f2b(dp2[DSTATE + nn]);
        }
    }
}

// ---------------------------------------------------------------- selective scan with FORCED 4-deep load pipeline
// Round-0 stream set (all dense bf16 reads: ut, dlt, szt, Bt, Ct — FETCH-optimal 53 MB).
// The compiler collapsed round-0's software pipeline (VGPR=48 < the 64 the dbuf needs):
// loads were sunk to their uses and every chunk stalled ~900cy on HBM with only 2 waves/SIMD.
// Fix: 4 rotating chunk buffers (raw u16 payloads only — converts stay in proc) with
// __builtin_amdgcn_sched_barrier(0) after each load-issue so loads CANNOT sink below the
// previous chunk's VALU. Prefetch distance = 3 chunks (~1900 cy) > HBM miss latency.
#define SCHUNK 16

struct ChunkBuf {
    bf16x8 u0, u1, d0, d1, b0, b1, c0, c1;
    u16 uo_r, szo_r;
};

__global__ __launch_bounds__(256, 2) void scan_fused(u16* __restrict__ y_re,
                                                     const u16* __restrict__ ut,
                                                     const u16* __restrict__ dlt,
                                                     const u16* __restrict__ Bt,
                                                     const u16* __restrict__ Ct,
                                                     const u16* __restrict__ szt,
                                                     const float* __restrict__ Alog,
                                                     const float* __restrict__ Dp) {
    int tid = threadIdx.x;
    int pair = tid >> 4, n = tid & 15;
    int blk = blockIdx.x;
    int b = blk >> 6;
    int e = ((blk & 63) << 4) + pair;
    float a2 = -__expf(Alog[e * DSTATE + n]) * 1.44269504f;   // fold log2e: dA = exp2(dl*a2)
    float dpe = Dp[e];
    const u16* urow  = ut  + ((size_t)b * DINNER + e) * SEQ;
    const u16* dlrow = dlt + ((size_t)b * DINNER + e) * SEQ;
    const u16* szrow = szt + ((size_t)b * DINNER + e) * SEQ;
    const u16* Brow  = Bt + ((size_t)b * DSTATE + n) * SEQ;
    const u16* Crow  = Ct + ((size_t)b * DSTATE + n) * SEQ;
    // lane n stores t = c*16+n for its pair: scatter over 16 rows
    u16* ystore = y_re + ((size_t)b * SEQ + n) * DINNER + e;

    // per-lane 0/1 mask: lane n keeps time-step j==n of each chunk (1 fma/t)
    float msk[16];
    #pragma unroll
    for (int j = 0; j < 16; ++j) msk[j] = (n == j) ? 1.f : 0.f;

    float h = 0.f;
    ChunkBuf bufA, bufB, bufC, bufD;

    auto load = [&](int c, ChunkBuf& R) {
        R.u0 = *(const bf16x8*)(urow + c * SCHUNK);
        R.u1 = *(const bf16x8*)(urow + c * SCHUNK + 8);
        R.d0 = *(const bf16x8*)(dlrow + c * SCHUNK);
        R.d1 = *(const bf16x8*)(dlrow + c * SCHUNK + 8);
        R.b0 = *(const bf16x8*)(Brow + c * SCHUNK);
        R.b1 = *(const bf16x8*)(Brow + c * SCHUNK + 8);
        R.c0 = *(const bf16x8*)(Crow + c * SCHUNK);
        R.c1 = *(const bf16x8*)(Crow + c * SCHUNK + 8);
        R.uo_r  = urow[c * SCHUNK + n];    // lane n's own t (same cacheline as u0/u1)
        R.szo_r = szrow[c * SCHUNK + n];
    };
    auto proc = [&](int c, const ChunkBuf& R) {
        float keep = 0.f;
        #pragma unroll
        for (int j = 0; j < SCHUNK; ++j) {
            float uf = b2f((u16)((j < 8) ? R.u0[j] : R.u1[j - 8]));
            float dl = b2f((u16)((j < 8) ? R.d0[j] : R.d1[j - 8]));
            float dA = __builtin_amdgcn_exp2f(dl * a2);
            h = dA * h + (dl * uf) * b2f((u16)((j < 8) ? R.b0[j] : R.b1[j - 8]));
            float yp = sum16(h * b2f((u16)((j < 8) ? R.c0[j] : R.c1[j - 8])));
            keep += yp * msk[j];   // lane n keeps its own t's value
        }
        ystore[(size_t)c * SCHUNK * DINNER] =
            f2b((keep + b2f(R.uo_r) * dpe) * b2f(R.szo_r));
    };

    const int nc = SEQ / SCHUNK;   // 128, divisible by 4
    load(0, bufA);
    load(1, bufB);
    load(2, bufC);
    __builtin_amdgcn_sched_barrier(0);
    for (int c = 0; c < nc; c += 4) {
        int c3 = c + 3, c4 = c + 4, c5 = c + 5, c6 = c + 6;
        c4 = (c4 < nc) ? c4 : nc - 1;   // tail: redundant reloads of last chunk (cheap, branch-free)
        c5 = (c5 < nc) ? c5 : nc - 1;
        c6 = (c6 < nc) ? c6 : nc - 1;
        load(c3, bufD);  __builtin_amdgcn_sched_barrier(0);  proc(c,     bufA);
        load(c4, bufA);  __builtin_amdgcn_sched_barrier(0);  proc(c + 1, bufB);
        load(c5, bufB);  __builtin_amdgcn_sched_barrier(0);  proc(c + 2, bufC);
        load(c6, bufC);  __builtin_amdgcn_sched_barrier(0);  proc(c + 3, bufD);
    }
}

// ---------------------------------------------------------------- launch
extern "C" void kernel_launch(void* const* d_in, const int* in_sizes, int n_in,
                              void* d_out, int out_size, void* d_ws, size_t ws_size,
                              hipStream_t stream) {
    const float* x_in   = (const float*)d_in[0];
    const float* ln_w   = (const float*)d_in[1];
    const float* ln_b   = (const float*)d_in[2];
    const float* inw    = (const float*)d_in[3];
    const float* convw  = (const float*)d_in[4];
    const float* convb  = (const float*)d_in[5];
    const float* xpw    = (const float*)d_in[6];
    const float* dtw    = (const float*)d_in[7];
    const float* dtb    = (const float*)d_in[8];
    const float* Alog   = (const float*)d_in[9];
    const float* Dp     = (const float*)d_in[10];
    const float* outw   = (const float*)d_in[11];
    float* out = (float*)d_out;

    // workspace carve-up — 212,860,928 B (exactly the proven round-0 footprint)
    char* p = (char*)d_ws;
    u16* xi_re = (u16*)p;               p += (size_t)ROWS * DINNER * 2;          //  33,554,432
    u16* sz_re = (u16*)p;               p += (size_t)ROWS * DINNER * 2;          //  33,554,432
    u16* y_re  = (u16*)p;               p += (size_t)ROWS * DINNER * 2;          //  33,554,432
    float* dbc = (float*)p;             p += (size_t)ROWS * DBCW * 4;            //   4,194,304
    u16* dlt   = (u16*)p;               p += (size_t)B_SZ * DINNER * SEQ * 2;    //  33,554,432
    u16* u_re  = dlt;                   // alias: u_re consumed by gemm_xp before delta writes dlt
    u16* Bt    = (u16*)p;               p += (size_t)B_SZ * DSTATE * SEQ * 2;    //     524,288
    u16* xwbf  = Bt;                    // alias: xwbf consumed by gemm_xp before delta_bct writes Bt
    u16* Ct    = (u16*)p;               p += (size_t)B_SZ * DSTATE * SEQ * 2;    //     524,288
    u16* ut    = (u16*)p;               p += (size_t)B_SZ * DINNER * SEQ * 2;    //  33,554,432
    u16* xnbf  = ut;                    // alias: xn (16.8 MB) dead before u_t writes ut
    u16* szt   = (u16*)p;               p += (size_t)B_SZ * DINNER * SEQ * 2;    //  33,554,432
    u16* inwbf = (u16*)p;               p += (size_t)N_INW * 2;                  //   4,194,304
    u16* outwbf = (u16*)p;              p += (size_t)N_OUTW * 2;                 //   2,097,152

    const dim3 blk256(256);
    const int n_conv = N_INW + N_OUTW + N_XW;

    for (int i = 0; i < DEPTH; ++i) {
        const float* x_cur = (i == 0) ? x_in : out;
        const float* lw  = ln_w  + (size_t)i * DMODEL;
        const float* lb  = ln_b  + (size_t)i * DMODEL;
        const float* iw  = inw   + (size_t)i * 2 * DINNER * DMODEL;
        const float* cw  = convw + (size_t)i * DINNER * DCONV;
        const float* cb  = convb + (size_t)i * DINNER;
        const float* xw  = xpw   + (size_t)i * DBCW * DINNER;
        const float* dw  = dtw   + (size_t)i * DINNER * DTRANK;
        const float* db  = dtb   + (size_t)i * DINNER;
        const float* Al  = Alog  + (size_t)i * DINNER * DSTATE;
        const float* Dpp = Dp    + (size_t)i * DINNER;
        const float* ow  = outw  + (size_t)i * DMODEL * DINNER;

        // 0. all weight conversions in one launch (xwbf parked in Bt region)
        conv_weights<<<(n_conv + 255) / 256, blk256, 0, stream>>>(
            iw, ow, xw, inwbf, outwbf, xwbf);
        // 1. LayerNorm -> bf16 (into ut region; dead before u_t writes)
        ln_kernel<<<ROWS, blk256, 0, stream>>>(x_cur, lw, lb, xnbf);
        // 2. in_proj (bf16 MFMA): xi_re = xn@iw_x^T, sz_re = silu(xn@iw_z^T)
        gemm_in<<<dim3(2 * DINNER / 128, ROWS / 128), blk256, 0, stream>>>(
            xnbf, inwbf, xi_re, sz_re);
        // 3. u precompute: ut[b,e,t] + u_re[r,e] + szt[b,e,t]
        u_t_kernel<<<dim3(SEQ / 64, DINNER / 64, B_SZ), blk256, 0, stream>>>(
            xi_re, sz_re, cw, cb, ut, u_re, szt);
        // 4. x_proj (bf16 MFMA, N=64): dbc = u_re @ xw^T
        gemm_xp_bf16<<<ROWS / 128, blk256, 0, stream>>>(u_re, xwbf, dbc);
        // 5. delta + B/C precompute (overwrites u_re/xwbf regions, now dead)
        delta_bct_kernel<<<dim3(DINNER / 64, SEQ / 256, B_SZ), blk256, 0, stream>>>(
            dbc, dw, db, dlt, Bt, Ct);
        // 6. scan + register-keep gated output: y_re bf16
        scan_fused<<<(B_SZ * DINNER) / 16, blk256, 0, stream>>>(
            y_re, ut, dlt, Bt, Ct, szt, Al, Dpp);
        // 7. out_proj (bf16 MFMA) + residual
        gemm_out<<<dim3(DMODEL / 128, ROWS / 128), blk256, 0, stream>>>(
            y_re, outwbf, x_cur, out);
    }
}